// Round 7
// baseline (1491.650 us; speedup 1.0000x reference)
//
#include <hip/hip_runtime.h>
#include <hip/hip_bf16.h>

typedef __attribute__((ext_vector_type(4))) float  f32x4;
typedef __attribute__((ext_vector_type(8))) short  s16x8;
typedef __attribute__((ext_vector_type(4))) short  s16x4;

union BH4 { s16x4 v; __hip_bfloat16 h[4]; };
union BH8 { s16x8 v; __hip_bfloat16 h[8]; };

#define MFMA16(A,B,C) __builtin_amdgcn_mfma_f32_16x16x32_bf16((A),(B),(C),0,0,0)

__device__ __forceinline__ float sigm(float x) { return 1.0f / (1.0f + __expf(-x)); }

// [rows][256] bf16 (512 B rows): XOR row into 16B slot (bank-conflict fix)
__device__ __forceinline__ int xad(int r, int byteInRow) {
  return ((r << 9) + byteInRow) ^ ((r & 7) << 4);
}
// chunk buffers: [rows][64] bf16 (128 B rows): slot16 ^= (i&7)
__device__ __forceinline__ int cad64(int i, int k) {   // k = bf16 idx 0..63
  return (i << 7) + ((((k >> 3) ^ (i & 7)) << 4) | ((k & 7) << 1));
}

// fp32 weight [256][256] -> bf16 MFMA B-fragment order:
// dst[((ct*8+ks)*64+lane)*8 + j] = w[ct*16 + (lane&15)][ks*32 + (lane>>4)*8 + j]
__global__ void wfrag_kernel(const float* __restrict__ w_in,
                             const float* __restrict__ w_gate,
                             const float* __restrict__ w_out,
                             __hip_bfloat16* __restrict__ dst) {
  const int lane = threadIdx.x;         // 64
  const int fid  = blockIdx.x;          // 0..127 = ct*8+ks
  const int m    = blockIdx.y;          // 0:wa 1:wb 2:wg 3:wo
  const float* src = (m == 0) ? w_in : (m == 1) ? (w_in + 65536)
                    : (m == 2) ? w_gate : w_out;
  const int e  = (fid >> 3) * 16 + (lane & 15);
  const int d0 = (fid & 7) * 32 + (lane >> 4) * 8;
  BH8 u;
  #pragma unroll
  for (int j = 0; j < 8; ++j) u.h[j] = __float2bfloat16(src[e * 256 + d0 + j]);
  *reinterpret_cast<s16x8*>(dst + (size_t)m * 65536 + ((size_t)fid * 64 + lane) * 8) = u.v;
}

// K1: x = LN(pair) -> xws in A-fragment order:
// xws[((s*16+rt)*8+ks)*512 + lane*8 + j] = x[s][rt*16 + (lane&15)][ks*32 + (lane>>4)*8 + j]
__global__ __launch_bounds__(256) void ln_kernel(
    const float* __restrict__ pair, const float* __restrict__ gamma,
    const float* __restrict__ beta, __hip_bfloat16* __restrict__ xws)
{
  __shared__ char Xl[8192];
  const int t  = threadIdx.x;
  const int s  = blockIdx.x >> 4;
  const int rt = blockIdx.x & 15;
  const int r  = t >> 4;                 // local row 0..15
  const int c0 = (t & 15) * 16;
  const float* src = pair + (((size_t)s * 256 + rt * 16 + r) * 256 + c0);
  float v[16];
  #pragma unroll
  for (int i = 0; i < 4; ++i) {
    const float4 f = *reinterpret_cast<const float4*>(src + i * 4);
    v[i*4+0]=f.x; v[i*4+1]=f.y; v[i*4+2]=f.z; v[i*4+3]=f.w;
  }
  float sm = 0.f, ss = 0.f;
  #pragma unroll
  for (int i = 0; i < 16; ++i) { sm += v[i]; ss += v[i]*v[i]; }
  #pragma unroll
  for (int m = 1; m < 16; m <<= 1) { sm += __shfl_xor(sm, m); ss += __shfl_xor(ss, m); }
  const float mean = sm * (1.f/256.f);
  const float rstd = rsqrtf(ss * (1.f/256.f) - mean*mean + 1e-5f);
  #pragma unroll
  for (int i = 0; i < 4; ++i) {
    const float4 gm = *reinterpret_cast<const float4*>(gamma + c0 + i*4);
    const float4 bt = *reinterpret_cast<const float4*>(beta  + c0 + i*4);
    BH4 o;
    o.h[0] = __float2bfloat16((v[i*4+0]-mean)*rstd*gm.x + bt.x);
    o.h[1] = __float2bfloat16((v[i*4+1]-mean)*rstd*gm.y + bt.y);
    o.h[2] = __float2bfloat16((v[i*4+2]-mean)*rstd*gm.z + bt.z);
    o.h[3] = __float2bfloat16((v[i*4+3]-mean)*rstd*gm.w + bt.w);
    *reinterpret_cast<s16x4*>(Xl + xad(r, (c0 + i*4)*2)) = o.v;
  }
  __syncthreads();
  #pragma unroll
  for (int p = 0; p < 2; ++p) {
    const int u  = t + p * 256;
    const int ks = u >> 6;
    const int lp = u & 63;
    const s16x8 f = *reinterpret_cast<const s16x8*>(
        Xl + xad(lp & 15, ks*64 + ((lp>>4)&3)*16));
    *reinterpret_cast<s16x8*>(xws + ((((size_t)s*16 + rt)*8 + ks)*64 + lp)*8) = f;
  }
}

// K2: block = QUARTER-slice (64 tri rows x 256 cols), 512 thr (8 waves).
// launch_bounds(512,4): flat-wgs 512 = 2 waves/SIMD per block; waves/eu=4 ->
// 128 unified regs/wave, 2 blocks/CU = 16 waves/CU.
// Register plan: arch-side <=~50 (ks-outer out phase), acc-side <=64 (og+oo).
__global__ __launch_bounds__(512, 4) void tri_fused(
    const __hip_bfloat16* __restrict__ xws,
    const __hip_bfloat16* __restrict__ wfrag,
    const float* __restrict__ gamma, const float* __restrict__ beta,
    float* __restrict__ out)
{
  extern __shared__ __align__(16) char lds[];
  char*  const XS = lds;                      // 32768 B : x-chunk frags (linear)
  char*  const AC = lds + 32768;              //  8192 B : a^T chunk [64][64] swz
  char*  const BC = lds + 40960;              // 32768 B : b^T chunk [256][64] swz
  float* const ST = (float*)(lds + 73728);    //  1024 B : LN partial stats
  char*  const SW = lds;                      // 32768 B : ln(tri) [64][256] (overlay)

  const int raw = blockIdx.x;                 // 2048 blocks
  const int xcd = raw & 7, o = raw >> 3;
  const int s   = xcd * 64 + (o >> 2);        // slice (4 siblings same XCD, adjacent)
  const int qt  = o & 3;                      // quarter: tri rows qt*64 .. qt*64+63

  const int tid = threadIdx.x, lane = tid & 63, w = tid >> 6;   // 8 waves
  const int l15 = lane & 15, lh = lane >> 4;
  const int rtw = w >> 1, ch = w & 1;         // wave tile: rows rtw*16(+qt*64), cols ch*128

  const __hip_bfloat16* const wa = wfrag;
  const __hip_bfloat16* const wb = wfrag + 65536;
  const __hip_bfloat16* const wg = wfrag + 131072;
  const __hip_bfloat16* const wo = wfrag + 196608;
  const __hip_bfloat16* const xs = xws + (size_t)s * 65536;
  const char* const xsb = (const char*)xs;

  f32x4 tri[8];
  #pragma unroll
  for (int jt = 0; jt < 8; ++jt) tri[jt] = (f32x4){0.f,0.f,0.f,0.f};

  // ---- prologue: stage x-chunk 0 (32 KB linear; xws layout is frag-linear)
  {
    s16x8 st[4];
    #pragma unroll
    for (int p = 0; p < 4; ++p)
      st[p] = *reinterpret_cast<const s16x8*>(xsb + p*8192 + tid*16);
    #pragma unroll
    for (int p = 0; p < 4; ++p)
      *reinterpret_cast<s16x8*>(XS + p*8192 + tid*16) = st[p];
  }
  __syncthreads();

  for (int c = 0; c < 4; ++c) {
    // ---- chunk GEMM: 80 jobs (16 a, 64 b), 10 per wave, 4-reg acc each
    #pragma unroll
    for (int j = 0; j < 10; ++j) {
      const int jid = w + 8*j;                // 0..79
      const bool isA = (jid < 16);
      const int e   = isA ? jid : (jid - 16);
      const int ctl = e >> 2;                 // a: 0..3 (quarter row-tiles)  b: 0..15
      const int rt  = e & 3;                  // k-row-tile within chunk
      const int ctg = isA ? (qt*4 + ctl) : ctl;
      const __hip_bfloat16* const wsrc = isA ? wa : wb;
      char* const dstb = isA ? AC : BC;
      f32x4 acc = (f32x4){0.f,0.f,0.f,0.f};
      #pragma unroll
      for (int ks = 0; ks < 8; ++ks) {
        const s16x8 Bf = *reinterpret_cast<const s16x8*>(
            wsrc + (((size_t)ctg*8 + ks)*64 + lane)*8);
        const s16x8 Af = *reinterpret_cast<const s16x8*>(
            XS + ((rt*8 + ks)*64 + lane)*16);
        acc = MFMA16(Af, Bf, acc);
      }
      BH4 ov;
      #pragma unroll
      for (int q = 0; q < 4; ++q) ov.h[q] = __float2bfloat16(acc[q] * sigm(acc[q]));
      *reinterpret_cast<s16x4*>(dstb + cad64(ctl*16 + l15, rt*16 + lh*4)) = ov.v;
    }
    __syncthreads();   // AC/BC ready; all XS reads of chunk c done

    // issue next chunk's staging loads early (hide under tri accum)
    s16x8 st[4];
    if (c < 3) {
      #pragma unroll
      for (int p = 0; p < 4; ++p)
        st[p] = *reinterpret_cast<const s16x8*>(xsb + (c+1)*32768 + p*8192 + tid*16);
    }
    // ---- tri accumulation (K=64): 16 MFMAs into 32-reg acc
    #pragma unroll
    for (int kss = 0; kss < 2; ++kss) {
      const s16x8 ta = *reinterpret_cast<const s16x8*>(
          AC + cad64(rtw*16 + l15, kss*32 + lh*8));
      #pragma unroll
      for (int jt = 0; jt < 8; ++jt) {
        const s16x8 tb = *reinterpret_cast<const s16x8*>(
            BC + cad64((ch*8 + jt)*16 + l15, kss*32 + lh*8));
        tri[jt] = MFMA16(ta, tb, tri[jt]);
      }
    }
    if (c < 3) {
      #pragma unroll
      for (int p = 0; p < 4; ++p)
        *reinterpret_cast<s16x8*>(XS + p*8192 + tid*16) = st[p];
    }
    __syncthreads();   // tri reads done + XS staging visible
  }

  // ---- LN(tri): in-wave partial over 128 cols, pair-exchange via ST
  float gr[8], br[8];
  #pragma unroll
  for (int jt = 0; jt < 8; ++jt) {
    gr[jt] = gamma[(ch*8 + jt)*16 + l15];
    br[jt] = beta [(ch*8 + jt)*16 + l15];
  }
  float psm[4], pss[4];
  #pragma unroll
  for (int q = 0; q < 4; ++q) {
    float sm = 0.f, ss = 0.f;
    #pragma unroll
    for (int jt = 0; jt < 8; ++jt) { const float v = tri[jt][q]; sm += v; ss += v*v; }
    #pragma unroll
    for (int m = 1; m < 16; m <<= 1) { sm += __shfl_xor(sm, m); ss += __shfl_xor(ss, m); }
    psm[q] = sm; pss[q] = ss;
  }
  if (l15 == 0) {
    #pragma unroll
    for (int q = 0; q < 4; ++q) {
      ST[((w*4 + lh)*4 + q)*2 + 0] = psm[q];
      ST[((w*4 + lh)*4 + q)*2 + 1] = pss[q];
    }
  }
  __syncthreads();
  float mean[4], rstd[4];
  {
    const int pw = w ^ 1;    // partner wave: same rows, other col-half
    #pragma unroll
    for (int q = 0; q < 4; ++q) {
      const float sm = psm[q] + ST[((pw*4 + lh)*4 + q)*2 + 0];
      const float ss = pss[q] + ST[((pw*4 + lh)*4 + q)*2 + 1];
      mean[q] = sm * (1.f/256.f);
      rstd[q] = rsqrtf(ss * (1.f/256.f) - mean[q]*mean[q] + 1e-5f);
    }
  }
  // stage ln(tri) bf16 into SW (overlays XS/AC — dead after barrier above)
  #pragma unroll
  for (int jt = 0; jt < 8; ++jt) {
    #pragma unroll
    for (int q = 0; q < 4; ++q) {
      const float vv = (tri[jt][q] - mean[q]) * rstd[q] * gr[jt] + br[jt];
      *reinterpret_cast<__hip_bfloat16*>(
          SW + xad(rtw*16 + lh*4 + q, ((ch*8 + jt)*16 + l15)*2)) = __float2bfloat16(vv);
    }
  }
  __syncthreads();

  // ---- out = (LN(tri) @ Wo^T) * sigmoid(x @ Wg^T)
  // ks-outer loop: arch-live = Ax,Aln,Bg,Bo (~16); og/oo[8] = 64 acc-side.
  f32x4 og[8], oo[8];
  #pragma unroll
  for (int t = 0; t < 8; ++t) { og[t] = (f32x4){0.f,0.f,0.f,0.f}; oo[t] = (f32x4){0.f,0.f,0.f,0.f}; }
  const int rtg = qt*4 + rtw;                 // global x row-tile
  #pragma unroll
  for (int ks = 0; ks < 8; ++ks) {
    const s16x8 Ax  = *reinterpret_cast<const s16x8*>(
        xs + (((size_t)rtg*8 + ks)*64 + lane)*8);
    const s16x8 Aln = *reinterpret_cast<const s16x8*>(
        SW + xad(rtw*16 + l15, ks*64 + lh*16));
    #pragma unroll
    for (int t = 0; t < 8; ++t) {
      const int ct = ch*8 + t;
      const s16x8 Bg = *reinterpret_cast<const s16x8*>(
          wg + (((size_t)ct*8 + ks)*64 + lane)*8);
      const s16x8 Bo = *reinterpret_cast<const s16x8*>(
          wo + (((size_t)ct*8 + ks)*64 + lane)*8);
      og[t] = MFMA16(Ax,  Bg, og[t]);
      oo[t] = MFMA16(Aln, Bo, oo[t]);
    }
  }
  #pragma unroll
  for (int t = 0; t < 8; ++t) {
    #pragma unroll
    for (int q = 0; q < 4; ++q) {
      const int row = qt*64 + rtw*16 + lh*4 + q;
      out[(size_t)s*65536 + (size_t)row*256 + (ch*8 + t)*16 + l15] =
          oo[t][q] * sigm(og[t][q]);
    }
  }
}

extern "C" void kernel_launch(void* const* d_in, const int* in_sizes, int n_in,
                              void* d_out, int out_size, void* d_ws, size_t ws_size,
                              hipStream_t stream) {
  const float* pair   = (const float*)d_in[0];
  const float* w_in   = (const float*)d_in[1];
  const float* w_gate = (const float*)d_in[2];
  const float* w_out  = (const float*)d_in[3];
  const float* gamma  = (const float*)d_in[4];
  const float* beta   = (const float*)d_in[5];
  float* out = (float*)d_out;

  __hip_bfloat16* wfrag = (__hip_bfloat16*)d_ws;                    // 512 KB
  __hip_bfloat16* xws   = (__hip_bfloat16*)((char*)d_ws + 524288);  // 67 MB

  (void)in_sizes; (void)n_in; (void)out_size; (void)ws_size;

  hipFuncSetAttribute(reinterpret_cast<const void*>(tri_fused),
                      hipFuncAttributeMaxDynamicSharedMemorySize, 74752);

  wfrag_kernel<<<dim3(128, 4), 64, 0, stream>>>(w_in, w_gate, w_out, wfrag);
  ln_kernel<<<8192, 256, 0, stream>>>(pair, gamma, beta, xws);
  tri_fused<<<2048, 512, 74752, stream>>>(xws, wfrag, gamma, beta, out);
}

// Round 8
// 239.579 us; speedup vs baseline: 6.2261x; 6.2261x over previous
//
#include <hip/hip_runtime.h>
#include <hip/hip_bf16.h>

typedef __attribute__((ext_vector_type(4))) float  f32x4;
typedef __attribute__((ext_vector_type(8))) short  s16x8;
typedef __attribute__((ext_vector_type(4))) short  s16x4;

union BH4 { s16x4 v; __hip_bfloat16 h[4]; };
union BH8 { s16x8 v; __hip_bfloat16 h[8]; };

#define MFMA16(A,B,C) __builtin_amdgcn_mfma_f32_16x16x32_bf16((A),(B),(C),0,0,0)

__device__ __forceinline__ float sigm(float x) { return 1.0f / (1.0f + __expf(-x)); }

// [rows][256] bf16 (512 B rows): XOR row into 16B slot (bank-conflict fix)
__device__ __forceinline__ int xad(int r, int byteInRow) {
  return ((r << 9) + byteInRow) ^ ((r & 7) << 4);
}
// chunk buffers: [rows][64] bf16 (128 B rows): slot16 ^= (i&7)   (fallback path)
__device__ __forceinline__ int cad64(int i, int k) {
  return (i << 7) + ((((k >> 3) ^ (i & 7)) << 4) | ((k & 7) << 1));
}

// fp32 weight [256][256] -> bf16 MFMA B-fragment order:
// dst[((m*16+ct)*8+ks)*512 + lane*8 + j] = w[ct*16+(lane&15)][ks*32+(lane>>4)*8+j]
__global__ void wfrag_kernel(const float* __restrict__ w_in,
                             const float* __restrict__ w_gate,
                             const float* __restrict__ w_out,
                             __hip_bfloat16* __restrict__ dst) {
  const int lane = threadIdx.x;         // 64
  const int fid  = blockIdx.x;          // 0..127 = ct*8+ks
  const int m    = blockIdx.y;          // 0:wa 1:wb 2:wg 3:wo
  const float* src = (m == 0) ? w_in : (m == 1) ? (w_in + 65536)
                    : (m == 2) ? w_gate : w_out;
  const int e  = (fid >> 3) * 16 + (lane & 15);
  const int d0 = (fid & 7) * 32 + (lane >> 4) * 8;
  BH8 u;
  #pragma unroll
  for (int j = 0; j < 8; ++j) u.h[j] = __float2bfloat16(src[e * 256 + d0 + j]);
  *reinterpret_cast<s16x8*>(dst + (size_t)m * 65536 + ((size_t)fid * 64 + lane) * 8) = u.v;
}

// ===================== STRATEGY A =====================
// K2: per-slice block (512 thr, 8 waves). Wave w owns token rows w*32..+31.
// LN -> x A-frags in regs; 48 ct GEMM tiles; scatter a/b as tri-operand frags,
// g as C-layout frags.
__global__ __launch_bounds__(512, 4) void k2_lnabg(
    const float* __restrict__ pair,
    const __hip_bfloat16* __restrict__ wfrag,
    const float* __restrict__ gamma, const float* __restrict__ beta,
    __hip_bfloat16* __restrict__ aT, __hip_bfloat16* __restrict__ bT,
    __hip_bfloat16* __restrict__ gws)
{
  __shared__ __align__(16) char lds[65536];      // 8 KB per wave, wave-private
  const int raw = blockIdx.x;                    // 512 blocks
  const int s   = (raw & 7) * 64 + (raw >> 3);   // XCD-pinned slice
  const int tid = threadIdx.x, lane = tid & 63, w = tid >> 6;
  const int l15 = lane & 15, lh = lane >> 4;
  char* const XW = lds + w * 8192;               // [16][256] bf16 swz

  const float4 gm = *reinterpret_cast<const float4*>(gamma + lane * 4);
  const float4 bt = *reinterpret_cast<const float4*>(beta  + lane * 4);

  s16x8 xr[2][8];                                // x A-frags, 64 VGPR
  #pragma unroll
  for (int rt = 0; rt < 2; ++rt) {
    #pragma unroll 1
    for (int rr = 0; rr < 16; ++rr) {
      const int r = w * 32 + rt * 16 + rr;
      const float4 v = *reinterpret_cast<const float4*>(
          pair + ((size_t)s * 256 + r) * 256 + lane * 4);
      float sm = v.x + v.y + v.z + v.w;
      float ss = v.x*v.x + v.y*v.y + v.z*v.z + v.w*v.w;
      #pragma unroll
      for (int m = 1; m < 64; m <<= 1) { sm += __shfl_xor(sm, m); ss += __shfl_xor(ss, m); }
      const float mean = sm * (1.f/256.f);
      const float rstd = rsqrtf(ss * (1.f/256.f) - mean*mean + 1e-5f);
      BH4 o;
      o.h[0] = __float2bfloat16((v.x - mean) * rstd * gm.x + bt.x);
      o.h[1] = __float2bfloat16((v.y - mean) * rstd * gm.y + bt.y);
      o.h[2] = __float2bfloat16((v.z - mean) * rstd * gm.z + bt.z);
      o.h[3] = __float2bfloat16((v.w - mean) * rstd * gm.w + bt.w);
      *reinterpret_cast<s16x4*>(XW + xad(rr, lane * 8)) = o.v;
    }
    #pragma unroll
    for (int ks = 0; ks < 8; ++ks)
      xr[rt][ks] = *reinterpret_cast<const s16x8*>(XW + xad(l15, ks*64 + lh*16));
  }

  // 48 ct: cg 0..15 = a (SiLU->aT frags), 16..31 = b (SiLU->bT), 32..47 = g (sigm)
  #pragma unroll 1
  for (int cg = 0; cg < 48; ++cg) {
    const int m  = cg >> 4;
    const int ct = cg & 15;
    f32x4 acc0 = (f32x4){0.f,0.f,0.f,0.f};
    f32x4 acc1 = (f32x4){0.f,0.f,0.f,0.f};
    #pragma unroll
    for (int ks = 0; ks < 8; ++ks) {
      const s16x8 Bf = *reinterpret_cast<const s16x8*>(
          wfrag + ((size_t)cg * 8 + ks) * 512 + lane * 8);
      acc0 = MFMA16(xr[0][ks], Bf, acc0);
      acc1 = MFMA16(xr[1][ks], Bf, acc1);
    }
    if (m < 2) {
      __hip_bfloat16* const dst = (m == 0) ? aT : bT;
      #pragma unroll
      for (int rt = 0; rt < 2; ++rt) {
        const f32x4 a = rt ? acc1 : acc0;
        BH4 o;
        #pragma unroll
        for (int q = 0; q < 4; ++q) o.h[q] = __float2bfloat16(a[q] * sigm(a[q]));
        const int lane2 = l15 + 16 * ((rt*2 + (lh >> 1)) & 3);
        // frag (s, it=ct, kt=w); value = act[k = w*32+rt*16+lh*4+q][i = ct*16+l15]
        *reinterpret_cast<s16x4*>(
            dst + (((size_t)s*16 + ct)*8 + w)*512 + lane2*8 + (lh & 1)*4) = o.v;
      }
    } else {
      #pragma unroll
      for (int rt = 0; rt < 2; ++rt) {
        const f32x4 a = rt ? acc1 : acc0;
        BH4 o;
        #pragma unroll
        for (int q = 0; q < 4; ++q) o.h[q] = __float2bfloat16(sigm(a[q]));
        const int rtg = w * 2 + rt;
        *reinterpret_cast<s16x4*>(
            gws + (((size_t)s*16 + rtg)*16 + ct)*256 + lane*4) = o.v;
      }
    }
  }
}

// K3: half-slice block (128 i x 256 j), 512 thr, 8 waves.
// Wave (r2=w>>1, ch=w&1): tri rows r2*32..+32, cols ch*128..+128.
// Frag-linear LDS staging (zero-conflict lane*16), K=32 chunks, reg prefetch.
__global__ __launch_bounds__(512, 4) void k3_tri(
    const __hip_bfloat16* __restrict__ aT, const __hip_bfloat16* __restrict__ bT,
    const __hip_bfloat16* __restrict__ gws, const __hip_bfloat16* __restrict__ wfrag,
    const float* __restrict__ gamma, const float* __restrict__ beta,
    float* __restrict__ out)
{
  extern __shared__ __align__(16) char lds[];    // 67584 B
  char*  const STG = lds;                        // 24576: 24 frags (8 a + 16 b)
  char*  const SW  = lds;                        // 65536 overlay: ln(tri) [128][256]
  float* const ST  = (float*)(lds + 65536);      // 2048: LN stats exchange

  const int raw = blockIdx.x;                    // 1024 blocks
  const int s   = (raw & 7) * 64 + ((raw >> 3) >> 1);
  const int h   = (raw >> 3) & 1;
  const int tid = threadIdx.x, lane = tid & 63, w = tid >> 6;
  const int l15 = lane & 15, lh = lane >> 4;
  const int r2 = w >> 1, ch = w & 1;

  f32x4 tri[2][8];
  #pragma unroll
  for (int rt = 0; rt < 2; ++rt)
    #pragma unroll
    for (int t = 0; t < 8; ++t) tri[rt][t] = (f32x4){0.f,0.f,0.f,0.f};

  // wave stages frags f = w*3+p (0..23): f<8 -> a it=f ; else b jt=f-8
  const int f0 = w * 3;
  s16x8 stg[3];
  #pragma unroll
  for (int p = 0; p < 3; ++p) {
    const int f = f0 + p;
    const __hip_bfloat16* src = (f < 8)
        ? aT + (((size_t)s*16 + h*8 + f)*8 + 0)*512
        : bT + (((size_t)s*16 + (f-8))*8 + 0)*512;
    stg[p] = *reinterpret_cast<const s16x8*>(src + lane*8);
  }

  for (int c = 0; c < 8; ++c) {
    #pragma unroll
    for (int p = 0; p < 3; ++p)
      *reinterpret_cast<s16x8*>(STG + (f0 + p)*1024 + lane*16) = stg[p];
    __syncthreads();
    if (c < 7) {
      #pragma unroll
      for (int p = 0; p < 3; ++p) {
        const int f = f0 + p;
        const __hip_bfloat16* src = (f < 8)
            ? aT + (((size_t)s*16 + h*8 + f)*8 + (c+1))*512
            : bT + (((size_t)s*16 + (f-8))*8 + (c+1))*512;
        stg[p] = *reinterpret_cast<const s16x8*>(src + lane*8);
      }
    }
    const s16x8 ta0 = *reinterpret_cast<const s16x8*>(STG + (r2*2+0)*1024 + lane*16);
    const s16x8 ta1 = *reinterpret_cast<const s16x8*>(STG + (r2*2+1)*1024 + lane*16);
    #pragma unroll
    for (int t = 0; t < 8; ++t) {
      const s16x8 tb = *reinterpret_cast<const s16x8*>(
          STG + (8 + ch*8 + t)*1024 + lane*16);
      tri[0][t] = MFMA16(ta0, tb, tri[0][t]);
      tri[1][t] = MFMA16(ta1, tb, tri[1][t]);
    }
    __syncthreads();
  }

  // LN(tri): partial over this wave's 128 cols + partner-wave (w^1) exchange
  float psm[2][4], pss[2][4];
  #pragma unroll
  for (int rt = 0; rt < 2; ++rt)
    #pragma unroll
    for (int q = 0; q < 4; ++q) {
      float sm = 0.f, ss = 0.f;
      #pragma unroll
      for (int t = 0; t < 8; ++t) { const float v = tri[rt][t][q]; sm += v; ss += v*v; }
      #pragma unroll
      for (int m = 1; m < 16; m <<= 1) { sm += __shfl_xor(sm, m); ss += __shfl_xor(ss, m); }
      psm[rt][q] = sm; pss[rt][q] = ss;
    }
  if (l15 == 0) {
    #pragma unroll
    for (int rt = 0; rt < 2; ++rt)
      #pragma unroll
      for (int q = 0; q < 4; ++q) {
        const int idx = ((w*2 + rt)*4 + lh)*4 + q;
        ST[idx*2 + 0] = psm[rt][q];
        ST[idx*2 + 1] = pss[rt][q];
      }
  }
  __syncthreads();
  float mean[2][4], rstd[2][4];
  #pragma unroll
  for (int rt = 0; rt < 2; ++rt)
    #pragma unroll
    for (int q = 0; q < 4; ++q) {
      const int idx = (((w ^ 1)*2 + rt)*4 + lh)*4 + q;
      const float sm = psm[rt][q] + ST[idx*2 + 0];
      const float ss = pss[rt][q] + ST[idx*2 + 1];
      mean[rt][q] = sm * (1.f/256.f);
      rstd[rt][q] = rsqrtf(ss * (1.f/256.f) - mean[rt][q]*mean[rt][q] + 1e-5f);
    }
  __syncthreads();   // ST reads done; STG fully dead -> SW may overlay
  #pragma unroll
  for (int t = 0; t < 8; ++t) {
    const int j = (ch*8 + t)*16 + l15;
    const float gmv = gamma[j], btv = beta[j];
    #pragma unroll
    for (int rt = 0; rt < 2; ++rt)
      #pragma unroll
      for (int q = 0; q < 4; ++q) {
        const int iloc = r2*32 + rt*16 + lh*4 + q;
        const float v = (tri[rt][t][q] - mean[rt][q]) * rstd[rt][q] * gmv + btv;
        *reinterpret_cast<__hip_bfloat16*>(SW + xad(iloc, j*2)) = __float2bfloat16(v);
      }
  }
  __syncthreads();

  // out = (LN(tri) @ wo^T) * g
  const __hip_bfloat16* const wo = wfrag + 196608;
  f32x4 oo[2][8];
  #pragma unroll
  for (int rt = 0; rt < 2; ++rt)
    #pragma unroll
    for (int t = 0; t < 8; ++t) oo[rt][t] = (f32x4){0.f,0.f,0.f,0.f};
  #pragma unroll
  for (int ks = 0; ks < 8; ++ks) {
    const s16x8 A0 = *reinterpret_cast<const s16x8*>(
        SW + xad(r2*32 +  0 + l15, ks*64 + lh*16));
    const s16x8 A1 = *reinterpret_cast<const s16x8*>(
        SW + xad(r2*32 + 16 + l15, ks*64 + lh*16));
    #pragma unroll
    for (int t = 0; t < 8; ++t) {
      const int cte = ch*8 + t;
      const s16x8 Bo = *reinterpret_cast<const s16x8*>(
          wo + ((size_t)(cte*8 + ks))*512 + lane*8);
      oo[0][t] = MFMA16(A0, Bo, oo[0][t]);
      oo[1][t] = MFMA16(A1, Bo, oo[1][t]);
    }
  }
  #pragma unroll
  for (int rt = 0; rt < 2; ++rt) {
    const int rtg = h*8 + r2*2 + rt;
    #pragma unroll
    for (int t = 0; t < 8; ++t) {
      BH4 gv;
      gv.v = *reinterpret_cast<const s16x4*>(
          gws + (((size_t)s*16 + rtg)*16 + (ch*8 + t))*256 + lane*4);
      #pragma unroll
      for (int q = 0; q < 4; ++q) {
        const int row = h*128 + r2*32 + rt*16 + lh*4 + q;
        out[((size_t)s*256 + row)*256 + (ch*8 + t)*16 + l15] =
            oo[rt][t][q] * __bfloat162float(gv.h[q]);
      }
    }
  }
}

// ===================== STRATEGY B (fallback, proven 228 us) =====================
__global__ __launch_bounds__(256) void ln_kernel(
    const float* __restrict__ pair, const float* __restrict__ gamma,
    const float* __restrict__ beta, __hip_bfloat16* __restrict__ xws)
{
  __shared__ char Xl[8192];
  const int t  = threadIdx.x;
  const int s  = blockIdx.x >> 4;
  const int rt = blockIdx.x & 15;
  const int r  = t >> 4;
  const int c0 = (t & 15) * 16;
  const float* src = pair + (((size_t)s * 256 + rt * 16 + r) * 256 + c0);
  float v[16];
  #pragma unroll
  for (int i = 0; i < 4; ++i) {
    const float4 f = *reinterpret_cast<const float4*>(src + i * 4);
    v[i*4+0]=f.x; v[i*4+1]=f.y; v[i*4+2]=f.z; v[i*4+3]=f.w;
  }
  float sm = 0.f, ss = 0.f;
  #pragma unroll
  for (int i = 0; i < 16; ++i) { sm += v[i]; ss += v[i]*v[i]; }
  #pragma unroll
  for (int m = 1; m < 16; m <<= 1) { sm += __shfl_xor(sm, m); ss += __shfl_xor(ss, m); }
  const float mean = sm * (1.f/256.f);
  const float rstd = rsqrtf(ss * (1.f/256.f) - mean*mean + 1e-5f);
  #pragma unroll
  for (int i = 0; i < 4; ++i) {
    const float4 gm = *reinterpret_cast<const float4*>(gamma + c0 + i*4);
    const float4 bt = *reinterpret_cast<const float4*>(beta  + c0 + i*4);
    BH4 o;
    o.h[0] = __float2bfloat16((v[i*4+0]-mean)*rstd*gm.x + bt.x);
    o.h[1] = __float2bfloat16((v[i*4+1]-mean)*rstd*gm.y + bt.y);
    o.h[2] = __float2bfloat16((v[i*4+2]-mean)*rstd*gm.z + bt.z);
    o.h[3] = __float2bfloat16((v[i*4+3]-mean)*rstd*gm.w + bt.w);
    *reinterpret_cast<s16x4*>(Xl + xad(r, (c0 + i*4)*2)) = o.v;
  }
  __syncthreads();
  #pragma unroll
  for (int p = 0; p < 2; ++p) {
    const int u  = t + p * 256;
    const int ks = u >> 6;
    const int lp = u & 63;
    const s16x8 f = *reinterpret_cast<const s16x8*>(
        Xl + xad(lp & 15, ks*64 + ((lp>>4)&3)*16));
    *reinterpret_cast<s16x8*>(xws + ((((size_t)s*16 + rt)*8 + ks)*64 + lp)*8) = f;
  }
}

__global__ __launch_bounds__(512, 2) void tri_fused_fb(
    const __hip_bfloat16* __restrict__ xws,
    const __hip_bfloat16* __restrict__ wfrag,
    const float* __restrict__ gamma, const float* __restrict__ beta,
    float* __restrict__ out)
{
  extern __shared__ __align__(16) char lds[];
  char* const XS = lds;
  char* const AC = lds + 32768;
  char* const BC = lds + 49152;
  char* const SW = lds;

  const int raw = blockIdx.x;
  const int xcd = raw & 7, o = raw >> 3;
  const int s   = xcd * 64 + (o >> 1);
  const int h   = o & 1;

  const int tid = threadIdx.x, lane = tid & 63, w = tid >> 6;
  const int l15 = lane & 15, lh = lane >> 4;

  const __hip_bfloat16* const wa = wfrag;
  const __hip_bfloat16* const wb = wfrag + 65536;
  const __hip_bfloat16* const wg = wfrag + 131072;
  const __hip_bfloat16* const wo = wfrag + 196608;
  const __hip_bfloat16* const xs = xws + (size_t)s * 65536;
  const char* const xsb = (const char*)xs;

  f32x4 tri[16];
  #pragma unroll
  for (int jt = 0; jt < 16; ++jt) tri[jt] = (f32x4){0.f,0.f,0.f,0.f};

  {
    s16x8 st[4];
    #pragma unroll
    for (int p = 0; p < 4; ++p)
      st[p] = *reinterpret_cast<const s16x8*>(xsb + p*8192 + tid*16);
    #pragma unroll
    for (int p = 0; p < 4; ++p)
      *reinterpret_cast<s16x8*>(XS + p*8192 + tid*16) = st[p];
  }
  __syncthreads();

  for (int c = 0; c < 4; ++c) {
    {
      const int ct = h*8 + w;
      f32x4 acc[4];
      #pragma unroll
      for (int rt = 0; rt < 4; ++rt) acc[rt] = (f32x4){0.f,0.f,0.f,0.f};
      #pragma unroll
      for (int ks = 0; ks < 8; ++ks) {
        const s16x8 Bf = *reinterpret_cast<const s16x8*>(wa + (((size_t)ct*8 + ks)*64 + lane)*8);
        #pragma unroll
        for (int rt = 0; rt < 4; ++rt) {
          const s16x8 Af = *reinterpret_cast<const s16x8*>(XS + ((rt*8 + ks)*64 + lane)*16);
          acc[rt] = MFMA16(Af, Bf, acc[rt]);
        }
      }
      #pragma unroll
      for (int rt = 0; rt < 4; ++rt) {
        const f32x4 vv = acc[rt];
        BH4 ov;
        #pragma unroll
        for (int q = 0; q < 4; ++q) ov.h[q] = __float2bfloat16(vv[q] * sigm(vv[q]));
        *reinterpret_cast<s16x4*>(AC + cad64(w*16 + l15, rt*16 + lh*4)) = ov.v;
      }
    }
    #pragma unroll
    for (int t = 0; t < 2; ++t) {
      const int ct = 2*w + t;
      f32x4 acc[4];
      #pragma unroll
      for (int rt = 0; rt < 4; ++rt) acc[rt] = (f32x4){0.f,0.f,0.f,0.f};
      #pragma unroll
      for (int ks = 0; ks < 8; ++ks) {
        const s16x8 Bf = *reinterpret_cast<const s16x8*>(wb + (((size_t)ct*8 + ks)*64 + lane)*8);
        #pragma unroll
        for (int rt = 0; rt < 4; ++rt) {
          const s16x8 Af = *reinterpret_cast<const s16x8*>(XS + ((rt*8 + ks)*64 + lane)*16);
          acc[rt] = MFMA16(Af, Bf, acc[rt]);
        }
      }
      #pragma unroll
      for (int rt = 0; rt < 4; ++rt) {
        const f32x4 vv = acc[rt];
        BH4 ov;
        #pragma unroll
        for (int q = 0; q < 4; ++q) ov.h[q] = __float2bfloat16(vv[q] * sigm(vv[q]));
        *reinterpret_cast<s16x4*>(BC + cad64(ct*16 + l15, rt*16 + lh*4)) = ov.v;
      }
    }
    __syncthreads();

    s16x8 st[4];
    if (c < 3) {
      #pragma unroll
      for (int p = 0; p < 4; ++p)
        st[p] = *reinterpret_cast<const s16x8*>(xsb + (c+1)*32768 + p*8192 + tid*16);
    }
    #pragma unroll
    for (int kss = 0; kss < 2; ++kss) {
      const s16x8 ta = *reinterpret_cast<const s16x8*>(AC + cad64(w*16 + l15, kss*32 + lh*8));
      #pragma unroll
      for (int jt = 0; jt < 16; ++jt) {
        const s16x8 tb = *reinterpret_cast<const s16x8*>(BC + cad64(jt*16 + l15, kss*32 + lh*8));
        tri[jt] = MFMA16(ta, tb, tri[jt]);
      }
    }
    if (c < 3) {
      #pragma unroll
      for (int p = 0; p < 4; ++p)
        *reinterpret_cast<s16x8*>(XS + p*8192 + tid*16) = st[p];
    }
    __syncthreads();
  }

  {
    float mean[4], rstd[4];
    #pragma unroll
    for (int q = 0; q < 4; ++q) {
      float sm = 0.f, ss = 0.f;
      #pragma unroll
      for (int jt = 0; jt < 16; ++jt) { const float x = tri[jt][q]; sm += x; ss += x*x; }
      #pragma unroll
      for (int m = 1; m < 16; m <<= 1) { sm += __shfl_xor(sm, m); ss += __shfl_xor(ss, m); }
      mean[q] = sm * (1.f/256.f);
      rstd[q] = rsqrtf(ss * (1.f/256.f) - mean[q]*mean[q] + 1e-5f);
    }
    #pragma unroll
    for (int jt = 0; jt < 16; ++jt) {
      const float gm = gamma[jt*16 + l15];
      const float bt = beta [jt*16 + l15];
      #pragma unroll
      for (int q = 0; q < 4; ++q) {
        const float vv = (tri[jt][q] - mean[q]) * rstd[q] * gm + bt;
        *reinterpret_cast<__hip_bfloat16*>(
            SW + xad(w*16 + lh*4 + q, (jt*16 + l15)*2)) = __float2bfloat16(vv);
      }
    }
  }
  __syncthreads();

  #pragma unroll
  for (int half = 0; half < 2; ++half) {
    #pragma unroll
    for (int t = 0; t < 2; ++t) {
      const int ct = 2*w + t;
      f32x4 og[4], oo[4];
      #pragma unroll
      for (int rt = 0; rt < 4; ++rt) { og[rt] = (f32x4){0.f,0.f,0.f,0.f}; oo[rt] = (f32x4){0.f,0.f,0.f,0.f}; }
      #pragma unroll
      for (int ks = 0; ks < 8; ++ks) {
        const s16x8 Bg = *reinterpret_cast<const s16x8*>(wg + (((size_t)ct*8 + ks)*64 + lane)*8);
        const s16x8 Bo = *reinterpret_cast<const s16x8*>(wo + (((size_t)ct*8 + ks)*64 + lane)*8);
        #pragma unroll
        for (int rt = 0; rt < 4; ++rt) {
          const int rtg = h*8 + half*4 + rt;
          const s16x8 Ax  = *reinterpret_cast<const s16x8*>(xs + (((size_t)rtg*8 + ks)*64 + lane)*8);
          const s16x8 Aln = *reinterpret_cast<const s16x8*>(
              SW + xad(half*64 + rt*16 + l15, ks*64 + lh*16));
          og[rt] = MFMA16(Ax,  Bg, og[rt]);
          oo[rt] = MFMA16(Aln, Bo, oo[rt]);
        }
      }
      #pragma unroll
      for (int rt = 0; rt < 4; ++rt) {
        #pragma unroll
        for (int q = 0; q < 4; ++q) {
          const int row = h*128 + half*64 + rt*16 + lh*4 + q;
          out[(size_t)s*65536 + (size_t)row*256 + ct*16 + l15] =
              oo[rt][q] * sigm(og[rt][q]);
        }
      }
    }
  }
}

extern "C" void kernel_launch(void* const* d_in, const int* in_sizes, int n_in,
                              void* d_out, int out_size, void* d_ws, size_t ws_size,
                              hipStream_t stream) {
  const float* pair   = (const float*)d_in[0];
  const float* w_in   = (const float*)d_in[1];
  const float* w_gate = (const float*)d_in[2];
  const float* w_out  = (const float*)d_in[3];
  const float* gamma  = (const float*)d_in[4];
  const float* beta   = (const float*)d_in[5];
  float* out = (float*)d_out;

  (void)in_sizes; (void)n_in; (void)out_size;

  __hip_bfloat16* wfrag = (__hip_bfloat16*)d_ws;                    // 512 KB

  wfrag_kernel<<<dim3(128, 4), 64, 0, stream>>>(w_in, w_gate, w_out, wfrag);

  if (ws_size >= 201850880ULL) {
    // Strategy A: decomposed streaming pipeline
    __hip_bfloat16* aT  = (__hip_bfloat16*)((char*)d_ws + 524288);
    __hip_bfloat16* bT  = (__hip_bfloat16*)((char*)d_ws + 524288 + 67108864);
    __hip_bfloat16* gws = (__hip_bfloat16*)((char*)d_ws + 524288 + 2*67108864);
    hipFuncSetAttribute(reinterpret_cast<const void*>(k3_tri),
                        hipFuncAttributeMaxDynamicSharedMemorySize, 67584);
    k2_lnabg<<<512, 512, 0, stream>>>(pair, wfrag, gamma, beta, aT, bT, gws);
    k3_tri<<<1024, 512, 67584, stream>>>(aT, bT, gws, wfrag, gamma, beta, out);
  } else {
    // Strategy B: proven fused pipeline (R3)
    __hip_bfloat16* xws = (__hip_bfloat16*)((char*)d_ws + 524288);
    hipFuncSetAttribute(reinterpret_cast<const void*>(tri_fused_fb),
                        hipFuncAttributeMaxDynamicSharedMemorySize, 81920);
    ln_kernel<<<8192, 256, 0, stream>>>(pair, gamma, beta, xws);
    tri_fused_fb<<<1024, 512, 81920, stream>>>(xws, wfrag, gamma, beta, out);
  }
}